// Round 2
// baseline (546.871 us; speedup 1.0000x reference)
//
#include <hip/hip_runtime.h>
#include <cstdint>
#include <cstddef>

#define DM 1024
#define HEADS 16
#define DHEAD 64
#define SEQ 2048
#define BATCH 2

typedef __bf16 bf16x8 __attribute__((ext_vector_type(8)));
typedef float  f32x4  __attribute__((ext_vector_type(4)));
typedef unsigned short u16;
typedef u16 u16x8 __attribute__((ext_vector_type(8)));

__device__ __forceinline__ float bf2f(u16 u){
    union { unsigned int i; float f; } v; v.i = ((unsigned int)u) << 16; return v.f;
}
__device__ __forceinline__ u16 f2bf(float f){
    union { float f; unsigned int i; } v; v.f = f;
    unsigned int r = v.i + 0x7FFF + ((v.i >> 16) & 1);   // RNE
    return (u16)(r >> 16);
}

// ---------------------------------------------------------------------------
// Dtype probe: decide whether d_in tensors are bf16 (flag=1) or fp32 (flag=0).
// bf16 N(0,1) data: exponent field of every u16 is ~[97,129].
// fp32 data read as u16: even indices are low mantissa halves (uniform bits).
// ---------------------------------------------------------------------------
__global__ void k_probe(const u16* __restrict__ q, int* __restrict__ flag){
    if (threadIdx.x == 0 && blockIdx.x == 0){
        int cnt = 0;
        for (int i = 0; i < 256; i += 2){
            int e = (q[i] >> 7) & 0xFF;
            if (e >= 90 && e <= 141) cnt++;
        }
        *flag = (cnt >= 64) ? 1 : 0;
    }
}

// ---------------------------------------------------------------------------
// Convert (fp32|bf16) -> bf16, flat array. n divisible by 2048.
// ---------------------------------------------------------------------------
__global__ __launch_bounds__(256) void k_cvt(const void* __restrict__ src,
                                             u16* __restrict__ dst,
                                             const int* __restrict__ flag, int n){
    int i = (blockIdx.x * 256 + threadIdx.x) * 8;
    if (i >= n) return;
    if (*flag){
        *(u16x8*)&dst[i] = *(const u16x8*)((const u16*)src + i);
    } else {
        const float* s = (const float*)src + i;
        u16x8 o;
        #pragma unroll
        for (int j = 0; j < 8; j++) o[j] = f2bf(s[j]);
        *(u16x8*)&dst[i] = o;
    }
}

// ---------------------------------------------------------------------------
// Transpose + convert: dst[c][r] = cvt(src[r][c]).  R,C multiples of 32.
// ---------------------------------------------------------------------------
__global__ void k_tcvt(const void* __restrict__ src, u16* __restrict__ dst,
                       const int* __restrict__ flag, int R, int C){
    __shared__ u16 tile[32][33];
    bool isbf = (*flag != 0);
    int c0 = blockIdx.x * 32, r0 = blockIdx.y * 32;
    int tx = threadIdx.x, ty = threadIdx.y;     // 32 x 8
    #pragma unroll
    for (int i = 0; i < 32; i += 8){
        size_t idx = (size_t)(r0 + ty + i) * C + c0 + tx;
        tile[ty + i][tx] = isbf ? ((const u16*)src)[idx] : f2bf(((const float*)src)[idx]);
    }
    __syncthreads();
    #pragma unroll
    for (int i = 0; i < 32; i += 8)
        dst[(size_t)(c0 + ty + i) * R + r0 + tx] = tile[tx][ty + i];
}

// ---------------------------------------------------------------------------
// Plain bf16 batched transpose: dst[b][c][r] = src[b][r][c].
// ---------------------------------------------------------------------------
__global__ void k_transpose(const u16* __restrict__ src, u16* __restrict__ dst,
                            int R, int C){
    __shared__ u16 tile[32][33];
    size_t boff = (size_t)blockIdx.z * R * C;
    src += boff; dst += boff;
    int c0 = blockIdx.x * 32, r0 = blockIdx.y * 32;
    int tx = threadIdx.x, ty = threadIdx.y;
    #pragma unroll
    for (int i = 0; i < 32; i += 8)
        tile[ty + i][tx] = src[(size_t)(r0 + ty + i) * C + c0 + tx];
    __syncthreads();
    #pragma unroll
    for (int i = 0; i < 32; i += 8)
        dst[(size_t)(c0 + ty + i) * R + r0 + tx] = tile[tx][ty + i];
}

// ---------------------------------------------------------------------------
// C[M,N] = A[M,K] * Bt[N,K]^T   (bf16 in, fp32 acc, bf16 out)
// 64x64 tile, BK=32, 256 threads = 4 waves, each wave a 32x32 quadrant.
// ---------------------------------------------------------------------------
__global__ __launch_bounds__(256) void k_gemm(const u16* __restrict__ A,
                                              const u16* __restrict__ Bt,
                                              u16* __restrict__ C,
                                              int M, int N, int K){
    __shared__ u16 lsA[64][40];   // stride 40 u16 = 80 B (16B-aligned rows)
    __shared__ u16 lsB[64][40];
    int m0 = blockIdx.y * 64, n0 = blockIdx.x * 64;
    int t = threadIdx.x;
    int lane = t & 63, w = t >> 6;
    int l15 = lane & 15, quad = lane >> 4;
    int mh = w & 1, nh = w >> 1;
    int srow = t >> 2, sch = t & 3;
    f32x4 acc[2][2] = {};
    for (int k0 = 0; k0 < K; k0 += 32){
        __syncthreads();
        *(u16x8*)&lsA[srow][sch * 8] = *(const u16x8*)&A [(size_t)(m0 + srow) * K + k0 + sch * 8];
        *(u16x8*)&lsB[srow][sch * 8] = *(const u16x8*)&Bt[(size_t)(n0 + srow) * K + k0 + sch * 8];
        __syncthreads();
        bf16x8 af[2], bfr[2];
        af [0] = *(const bf16x8*)&lsA[mh * 32 +      l15][quad * 8];
        af [1] = *(const bf16x8*)&lsA[mh * 32 + 16 + l15][quad * 8];
        bfr[0] = *(const bf16x8*)&lsB[nh * 32 +      l15][quad * 8];
        bfr[1] = *(const bf16x8*)&lsB[nh * 32 + 16 + l15][quad * 8];
        #pragma unroll
        for (int i = 0; i < 2; i++)
            #pragma unroll
            for (int j = 0; j < 2; j++)
                acc[i][j] = __builtin_amdgcn_mfma_f32_16x16x32_bf16(af[i], bfr[j], acc[i][j], 0, 0, 0);
    }
    #pragma unroll
    for (int i = 0; i < 2; i++)
        #pragma unroll
        for (int j = 0; j < 2; j++)
            #pragma unroll
            for (int r = 0; r < 4; r++){
                int m = m0 + mh * 32 + i * 16 + quad * 4 + r;   // D: row = quad*4+reg
                int n = n0 + nh * 32 + j * 16 + l15;            //    col = lane&15
                C[(size_t)m * N + n] = f2bf(acc[i][j][r]);
            }
}

// ---------------------------------------------------------------------------
// Fused attention, softmax over the HEADS axis (reference quirk: per-(q,k)
// normalization across 16 heads — purely local, no running max over k).
// Block = 1024 threads = 16 waves (wave h <-> head h), per (b, 16-row q-tile).
// ---------------------------------------------------------------------------
__global__ __launch_bounds__(1024) void k_attn(const u16* __restrict__ Qp,
                                               const u16* __restrict__ Kp,
                                               const u16* __restrict__ Vt,
                                               u16* __restrict__ ctx){
    __shared__ float s_lds[16 * 528];   // [h][q(16) stride 33][k(32)] fp32
    __shared__ u16   p_lds[16 * 640];   // [h][q(16) stride 40][k(32)] bf16
    int q0 = blockIdx.x * 16;
    int b  = blockIdx.y;
    int t = threadIdx.x;
    int h = t >> 6, lane = t & 63, l15 = lane & 15, quad = lane >> 4;

    const u16* qbase = Qp + ((size_t)(b * SEQ + q0 + l15)) * DM + h * DHEAD + quad * 8;
    bf16x8 aq0 = *(const bf16x8*)(qbase);
    bf16x8 aq1 = *(const bf16x8*)(qbase + 32);

    f32x4 cacc[4] = {};
    int sq = t >> 5, sk = t & 31;

    for (int k0 = 0; k0 < SEQ; k0 += 32){
        #pragma unroll
        for (int c = 0; c < 2; c++){
            f32x4 sc = {};
            const u16* kb = Kp + ((size_t)(b * SEQ + k0 + c * 16 + l15)) * DM + h * DHEAD + quad * 8;
            sc = __builtin_amdgcn_mfma_f32_16x16x32_bf16(aq0, *(const bf16x8*)kb,        sc, 0, 0, 0);
            sc = __builtin_amdgcn_mfma_f32_16x16x32_bf16(aq1, *(const bf16x8*)(kb + 32), sc, 0, 0, 0);
            #pragma unroll
            for (int r = 0; r < 4; r++)
                s_lds[h * 528 + (quad * 4 + r) * 33 + c * 16 + l15] = sc[r] * 0.125f;
        }
        __syncthreads();
        if (t < 512){
            float v[16];
            float m = -1e30f;
            #pragma unroll
            for (int hh = 0; hh < 16; hh++){
                v[hh] = s_lds[hh * 528 + sq * 33 + sk];
                m = fmaxf(m, v[hh]);
            }
            float sum = 0.f;
            #pragma unroll
            for (int hh = 0; hh < 16; hh++){
                v[hh] = exp2f((v[hh] - m) * 1.44269504f);
                sum += v[hh];
            }
            float rs = 1.0f / sum;
            #pragma unroll
            for (int hh = 0; hh < 16; hh++)
                p_lds[hh * 640 + sq * 40 + sk] = f2bf(v[hh] * rs);
        }
        __syncthreads();
        bf16x8 ap = *(const bf16x8*)&p_lds[h * 640 + l15 * 40 + quad * 8];
        const u16* vb = Vt + ((size_t)b * DM + h * DHEAD + l15) * SEQ + k0 + quad * 8;
        #pragma unroll
        for (int vt4 = 0; vt4 < 4; vt4++)
            cacc[vt4] = __builtin_amdgcn_mfma_f32_16x16x32_bf16(
                ap, *(const bf16x8*)(vb + (size_t)vt4 * 16 * SEQ), cacc[vt4], 0, 0, 0);
        // 2 barriers/iter suffice: next iter's s_lds/p_lds writes are ordered
        // against this iter's reads by the two barriers above.
    }
    #pragma unroll
    for (int vt4 = 0; vt4 < 4; vt4++)
        #pragma unroll
        for (int r = 0; r < 4; r++){
            int q = q0 + quad * 4 + r;
            int n = h * DHEAD + vt4 * 16 + l15;
            ctx[((size_t)b * SEQ + q) * DM + n] = f2bf(cacc[vt4][r]);
        }
}

// ---------------------------------------------------------------------------
// Residual + LayerNorm over last dim (1024). One block per row.
// Reads O (bf16 ws), raw input_Q / gamma / beta (dtype per flag),
// writes out in dtype per flag.
// ---------------------------------------------------------------------------
__global__ __launch_bounds__(256) void k_ln(const u16* __restrict__ O,
                                            const void* __restrict__ Qin,
                                            const void* __restrict__ gamma,
                                            const void* __restrict__ beta,
                                            void* __restrict__ out,
                                            const int* __restrict__ flag){
    __shared__ float red[4][2];
    bool isbf = (*flag != 0);
    int row = blockIdx.x;
    int t = threadIdx.x;
    const u16* op = O + (size_t)row * DM;
    float xv[4];
    float s1 = 0.f, s2 = 0.f;
    #pragma unroll
    for (int i = 0; i < 4; i++){
        int idx = i * 256 + t;
        float q = isbf ? bf2f(((const u16*)Qin)[(size_t)row * DM + idx])
                       : ((const float*)Qin)[(size_t)row * DM + idx];
        float x = bf2f(op[idx]) + q;
        xv[i] = x; s1 += x; s2 += x * x;
    }
    #pragma unroll
    for (int off = 32; off; off >>= 1){
        s1 += __shfl_down(s1, off);
        s2 += __shfl_down(s2, off);
    }
    int w = t >> 6, lane = t & 63;
    if (lane == 0){ red[w][0] = s1; red[w][1] = s2; }
    __syncthreads();
    float S1 = red[0][0] + red[1][0] + red[2][0] + red[3][0];
    float S2 = red[0][1] + red[1][1] + red[2][1] + red[3][1];
    float mu  = S1 * (1.0f / DM);
    float var = S2 * (1.0f / DM) - mu * mu;
    float rstd = rsqrtf(var + 1e-5f);
    #pragma unroll
    for (int i = 0; i < 4; i++){
        int idx = i * 256 + t;
        float g = isbf ? bf2f(((const u16*)gamma)[idx]) : ((const float*)gamma)[idx];
        float bb= isbf ? bf2f(((const u16*)beta )[idx]) : ((const float*)beta )[idx];
        float y = (xv[i] - mu) * rstd * g + bb;
        if (isbf) ((u16*)out)[(size_t)row * DM + idx] = f2bf(y);
        else      ((float*)out)[(size_t)row * DM + idx] = y;
    }
}

// ---------------------------------------------------------------------------
extern "C" void kernel_launch(void* const* d_in, const int* in_sizes, int n_in,
                              void* d_out, int out_size, void* d_ws, size_t ws_size,
                              hipStream_t stream){
    (void)in_sizes; (void)n_in; (void)out_size; (void)ws_size;
    const void* inQ = d_in[0];
    const void* inK = d_in[1];
    const void* inV = d_in[2];
    const void* wQ  = d_in[3];
    const void* wK  = d_in[4];
    const void* wV  = d_in[5];
    const void* wO  = d_in[6];
    const void* gma = d_in[7];
    const void* bta = d_in[8];

    int* flag = (int*)d_ws;
    u16* base = (u16*)d_ws + 64;               // 128 B header, keeps 16B alignment

    const size_t MB1 = 1024u * 1024u;          // elements
    const size_t M4  = 4u * MB1;
    u16* Qi  = base + 0;                       // [4096,1024] bf16 input_Q
    u16* Ki  = base + 1 * M4;                  // [4096,1024] bf16 input_K (-> Vt later)
    u16* Vi  = base + 2 * M4;                  // [4096,1024] bf16 input_V (-> cx later)
    u16* WtQ = base + 3 * M4;                  // [1024,1024] W^T each
    u16* WtK = WtQ + MB1;
    u16* WtV = WtQ + 2 * MB1;
    u16* WtO = WtQ + 3 * MB1;
    u16* Qp  = base + 4 * M4;
    u16* Kp  = base + 5 * M4;
    u16* Vp  = base + 6 * M4;                  // -> Ob later
    u16* Vt  = Ki;                             // [2][1024][2048], Ki dead by then
    u16* cx  = Vi;                             // Vi dead by then
    u16* Ob  = Vp;                             // Vp dead by then

    k_probe<<<1, 64, 0, stream>>>((const u16*)inQ, flag);

    const int nIn = BATCH * SEQ * DM;          // 4M
    k_cvt<<<nIn / (256 * 8), 256, 0, stream>>>(inQ, Qi, flag, nIn);
    k_cvt<<<nIn / (256 * 8), 256, 0, stream>>>(inK, Ki, flag, nIn);
    k_cvt<<<nIn / (256 * 8), 256, 0, stream>>>(inV, Vi, flag, nIn);

    dim3 tt(32, 8);
    k_tcvt<<<dim3(32, 32), tt, 0, stream>>>(wQ, WtQ, flag, 1024, 1024);
    k_tcvt<<<dim3(32, 32), tt, 0, stream>>>(wK, WtK, flag, 1024, 1024);
    k_tcvt<<<dim3(32, 32), tt, 0, stream>>>(wV, WtV, flag, 1024, 1024);
    k_tcvt<<<dim3(32, 32), tt, 0, stream>>>(wO, WtO, flag, 1024, 1024);

    k_gemm<<<dim3(16, 64), 256, 0, stream>>>(Qi, WtQ, Qp, 4096, 1024, 1024);
    k_gemm<<<dim3(16, 64), 256, 0, stream>>>(Ki, WtK, Kp, 4096, 1024, 1024);
    k_gemm<<<dim3(16, 64), 256, 0, stream>>>(Vi, WtV, Vp, 4096, 1024, 1024);

    k_transpose<<<dim3(32, 64, 2), tt, 0, stream>>>(Vp, Vt, 2048, 1024);

    k_attn<<<dim3(128, 2), 1024, 0, stream>>>(Qp, Kp, Vt, cx);

    k_gemm<<<dim3(16, 64), 256, 0, stream>>>(cx, WtO, Ob, 4096, 1024, 1024);

    k_ln<<<4096, 256, 0, stream>>>(Ob, inQ, gma, bta, d_out, flag);
}

// Round 3
// 442.072 us; speedup vs baseline: 1.2371x; 1.2371x over previous
//
#include <hip/hip_runtime.h>
#include <cstdint>
#include <cstddef>

#define DM 1024
#define HEADS 16
#define DHEAD 64
#define SEQ 2048
#define BATCH 2

typedef __bf16 bf16x8 __attribute__((ext_vector_type(8)));
typedef float  f32x4  __attribute__((ext_vector_type(4)));
typedef unsigned short u16;
typedef u16 u16x8 __attribute__((ext_vector_type(8)));

__device__ __forceinline__ float bf2f(u16 u){
    union { unsigned int i; float f; } v; v.i = ((unsigned int)u) << 16; return v.f;
}
__device__ __forceinline__ u16 f2bf(float f){
    union { float f; unsigned int i; } v; v.f = f;
    unsigned int r = v.i + 0x7FFF + ((v.i >> 16) & 1);   // RNE
    return (u16)(r >> 16);
}

// ---------------------------------------------------------------------------
// Dtype probe: inputs bf16 (flag=1) or fp32 (flag=0)?
// ---------------------------------------------------------------------------
__global__ void k_probe(const u16* __restrict__ q, int* __restrict__ flag){
    if (threadIdx.x == 0 && blockIdx.x == 0){
        int cnt = 0;
        for (int i = 0; i < 256; i += 2){
            int e = (q[i] >> 7) & 0xFF;
            if (e >= 90 && e <= 141) cnt++;
        }
        *flag = (cnt >= 64) ? 1 : 0;
    }
}

// ---------------------------------------------------------------------------
// Convert (fp32|bf16) -> bf16 flat. n divisible by 2048.
// ---------------------------------------------------------------------------
__global__ __launch_bounds__(256) void k_cvt(const void* __restrict__ src,
                                             u16* __restrict__ dst,
                                             const int* __restrict__ flag, int n){
    int i = (blockIdx.x * 256 + threadIdx.x) * 8;
    if (i >= n) return;
    if (*flag){
        *(u16x8*)&dst[i] = *(const u16x8*)((const u16*)src + i);
    } else {
        const float* s = (const float*)src + i;
        u16x8 o;
        #pragma unroll
        for (int j = 0; j < 8; j++) o[j] = f2bf(s[j]);
        *(u16x8*)&dst[i] = o;
    }
}

// ---------------------------------------------------------------------------
// Transpose + convert: dst[c][r] = cvt(src[r][c]).
// ---------------------------------------------------------------------------
__global__ void k_tcvt(const void* __restrict__ src, u16* __restrict__ dst,
                       const int* __restrict__ flag, int R, int C){
    __shared__ u16 tile[32][33];
    bool isbf = (*flag != 0);
    int c0 = blockIdx.x * 32, r0 = blockIdx.y * 32;
    int tx = threadIdx.x, ty = threadIdx.y;     // 32 x 8
    #pragma unroll
    for (int i = 0; i < 32; i += 8){
        size_t idx = (size_t)(r0 + ty + i) * C + c0 + tx;
        tile[ty + i][tx] = isbf ? ((const u16*)src)[idx] : f2bf(((const float*)src)[idx]);
    }
    __syncthreads();
    #pragma unroll
    for (int i = 0; i < 32; i += 8)
        dst[(size_t)(c0 + ty + i) * R + r0 + tx] = tile[tx][ty + i];
}

// ---------------------------------------------------------------------------
// Plain bf16 batched transpose: dst[b][c][r] = src[b][r][c].
// ---------------------------------------------------------------------------
__global__ void k_transpose(const u16* __restrict__ src, u16* __restrict__ dst,
                            int R, int C){
    __shared__ u16 tile[32][33];
    size_t boff = (size_t)blockIdx.z * R * C;
    src += boff; dst += boff;
    int c0 = blockIdx.x * 32, r0 = blockIdx.y * 32;
    int tx = threadIdx.x, ty = threadIdx.y;
    #pragma unroll
    for (int i = 0; i < 32; i += 8)
        tile[ty + i][tx] = src[(size_t)(r0 + ty + i) * C + c0 + tx];
    __syncthreads();
    #pragma unroll
    for (int i = 0; i < 32; i += 8)
        dst[(size_t)(c0 + ty + i) * R + r0 + tx] = tile[tx][ty + i];
}

// ---------------------------------------------------------------------------
// C[M,N] = A[M,K] * Bt[N,K]^T.  128x128 tile, BK=32, 256 threads = 4 waves,
// each wave computes a 64x64 quadrant (4x4 grid of 16x16x32 MFMAs).
// ---------------------------------------------------------------------------
__global__ __launch_bounds__(256) void k_gemm128(const u16* __restrict__ A,
                                                 const u16* __restrict__ Bt,
                                                 u16* __restrict__ C,
                                                 int M, int N, int K){
    __shared__ u16 lsA[128][40];   // +8 pad: frag b128 reads ~conflict-free
    __shared__ u16 lsB[128][40];
    int m0 = blockIdx.y * 128, n0 = blockIdx.x * 128;
    int t = threadIdx.x;
    int lane = t & 63, w = t >> 6;
    int l15 = lane & 15, quad = lane >> 4;
    int wm = (w & 1) * 64, wn = (w >> 1) * 64;
    f32x4 acc[4][4] = {};
    for (int k0 = 0; k0 < K; k0 += 32){
        __syncthreads();
        #pragma unroll
        for (int rnd = 0; rnd < 2; rnd++){
            int f = rnd * 2048 + t * 8;
            int row = f >> 5, col = f & 31;
            *(u16x8*)&lsA[row][col] = *(const u16x8*)&A [(size_t)(m0 + row) * K + k0 + col];
            *(u16x8*)&lsB[row][col] = *(const u16x8*)&Bt[(size_t)(n0 + row) * K + k0 + col];
        }
        __syncthreads();
        bf16x8 af[4], bfr[4];
        #pragma unroll
        for (int i = 0; i < 4; i++) af [i] = *(const bf16x8*)&lsA[wm + i * 16 + l15][quad * 8];
        #pragma unroll
        for (int j = 0; j < 4; j++) bfr[j] = *(const bf16x8*)&lsB[wn + j * 16 + l15][quad * 8];
        #pragma unroll
        for (int i = 0; i < 4; i++)
            #pragma unroll
            for (int j = 0; j < 4; j++)
                acc[i][j] = __builtin_amdgcn_mfma_f32_16x16x32_bf16(af[i], bfr[j], acc[i][j], 0, 0, 0);
    }
    #pragma unroll
    for (int i = 0; i < 4; i++)
        #pragma unroll
        for (int j = 0; j < 4; j++)
            #pragma unroll
            for (int r = 0; r < 4; r++){
                int m = m0 + wm + i * 16 + quad * 4 + r;   // D: row = quad*4+reg
                int n = n0 + wn + j * 16 + l15;            //    col = lane&15
                C[(size_t)m * N + n] = f2bf(acc[i][j][r]);
            }
}

// ---------------------------------------------------------------------------
// Fused attention v2, softmax over HEADS (per-(q,k) across 16 heads).
// 256 blocks: bid&3 -> (batch, k-chunk of 1024)   [XCD-L2 locality: all 32
// blocks resident on one XCD share a 4MB K/V chunk]; bid>>2 -> 32-row q-tile.
// Block = 16 waves (wave h = head h); each wave: 32 q-rows x 64 d.
// Writes bf16 partial ctx per k-chunk; k_reduce sums the two chunks.
// ---------------------------------------------------------------------------
__global__ __launch_bounds__(1024) void k_attn2(const u16* __restrict__ Qp,
                                                const u16* __restrict__ Kp,
                                                const u16* __restrict__ Vt,
                                                u16* __restrict__ ctxp0,
                                                u16* __restrict__ ctxp1){
    __shared__ u16 sbuf[16][32][40];   // scores bf16 (40KB)
    __shared__ u16 pbuf[16][32][40];   // P bf16      (40KB)
    int bid = blockIdx.x;
    int combo = bid & 3;
    int b = combo & 1, chunk = combo >> 1;
    int q0 = (bid >> 2) * 32;
    int t = threadIdx.x;
    int h = t >> 6, lane = t & 63, l15 = lane & 15, quad = lane >> 4;
    u16* outp = chunk ? ctxp1 : ctxp0;

    // persistent Q A-frags [sub][ch]
    bf16x8 qf[2][2];
    #pragma unroll
    for (int sub = 0; sub < 2; sub++)
        #pragma unroll
        for (int ch = 0; ch < 2; ch++)
            qf[sub][ch] = *(const bf16x8*)&Qp[((size_t)(b * SEQ + q0 + sub * 16 + l15)) * DM
                                             + h * DHEAD + ch * 32 + quad * 8];

    f32x4 oacc[2][4] = {};             // [sub][vt]
    int rq = t >> 5, rk = t & 31;      // this thread's softmax (q,k) pair

    int kbeg = chunk * 1024, kend = kbeg + 1024;
    for (int k0 = kbeg; k0 < kend; k0 += 32){
        // ---- scores S_h[32q x 32k] ----
        #pragma unroll
        for (int kt = 0; kt < 2; kt++){
            const u16* kb = Kp + ((size_t)(b * SEQ + k0 + kt * 16 + l15)) * DM + h * DHEAD + quad * 8;
            bf16x8 kf0 = *(const bf16x8*)(kb);
            bf16x8 kf1 = *(const bf16x8*)(kb + 32);
            #pragma unroll
            for (int sub = 0; sub < 2; sub++){
                f32x4 sc = {};
                sc = __builtin_amdgcn_mfma_f32_16x16x32_bf16(qf[sub][0], kf0, sc, 0, 0, 0);
                sc = __builtin_amdgcn_mfma_f32_16x16x32_bf16(qf[sub][1], kf1, sc, 0, 0, 0);
                #pragma unroll
                for (int r = 0; r < 4; r++)
                    sbuf[h][sub * 16 + quad * 4 + r][kt * 16 + l15] = f2bf(sc[r] * 0.125f);
            }
        }
        __syncthreads();
        // ---- softmax across 16 heads, one thread per (q,k) ----
        {
            float v[16];
            float m = -1e30f;
            #pragma unroll
            for (int hh = 0; hh < 16; hh++){
                v[hh] = bf2f(sbuf[hh][rq][rk]);
                m = fmaxf(m, v[hh]);
            }
            float sum = 0.f;
            #pragma unroll
            for (int hh = 0; hh < 16; hh++){
                v[hh] = exp2f((v[hh] - m) * 1.44269504f);
                sum += v[hh];
            }
            float rs = 1.0f / sum;
            #pragma unroll
            for (int hh = 0; hh < 16; hh++)
                pbuf[hh][rq][rk] = f2bf(v[hh] * rs);
        }
        __syncthreads();
        // ---- PV: O[32q x 64v] += P[32q x 32k] * V[32k x 64v] ----
        bf16x8 pf0 = *(const bf16x8*)&pbuf[h][     l15][quad * 8];
        bf16x8 pf1 = *(const bf16x8*)&pbuf[h][16 + l15][quad * 8];
        const u16* vb = Vt + ((size_t)b * DM + h * DHEAD + l15) * SEQ + k0 + quad * 8;
        #pragma unroll
        for (int vt = 0; vt < 4; vt++){
            bf16x8 vf = *(const bf16x8*)(vb + (size_t)vt * 16 * SEQ);
            oacc[0][vt] = __builtin_amdgcn_mfma_f32_16x16x32_bf16(pf0, vf, oacc[0][vt], 0, 0, 0);
            oacc[1][vt] = __builtin_amdgcn_mfma_f32_16x16x32_bf16(pf1, vf, oacc[1][vt], 0, 0, 0);
        }
        // 2 barriers/iter suffice: next iter's sbuf writes are ordered against
        // this iter's sbuf reads by B2; pbuf writes(i+1) vs pbuf reads(i) by B1(i+1).
    }
    #pragma unroll
    for (int sub = 0; sub < 2; sub++)
        #pragma unroll
        for (int vt = 0; vt < 4; vt++)
            #pragma unroll
            for (int r = 0; r < 4; r++){
                int q = q0 + sub * 16 + quad * 4 + r;
                int n = h * DHEAD + vt * 16 + l15;
                outp[((size_t)b * SEQ + q) * DM + n] = f2bf(oacc[sub][vt][r]);
            }
}

// ---------------------------------------------------------------------------
// cx = ctxp0 + ctxp1 (bf16)
// ---------------------------------------------------------------------------
__global__ __launch_bounds__(256) void k_reduce(const u16* __restrict__ a,
                                                const u16* __restrict__ b,
                                                u16* __restrict__ dst, int n){
    int i = (blockIdx.x * 256 + threadIdx.x) * 8;
    if (i >= n) return;
    u16x8 x = *(const u16x8*)&a[i];
    u16x8 y = *(const u16x8*)&b[i];
    u16x8 o;
    #pragma unroll
    for (int j = 0; j < 8; j++) o[j] = f2bf(bf2f(x[j]) + bf2f(y[j]));
    *(u16x8*)&dst[i] = o;
}

// ---------------------------------------------------------------------------
// Residual + LayerNorm over last dim (1024). One block per row.
// ---------------------------------------------------------------------------
__global__ __launch_bounds__(256) void k_ln(const u16* __restrict__ O,
                                            const void* __restrict__ Qin,
                                            const void* __restrict__ gamma,
                                            const void* __restrict__ beta,
                                            void* __restrict__ out,
                                            const int* __restrict__ flag){
    __shared__ float red[4][2];
    bool isbf = (*flag != 0);
    int row = blockIdx.x;
    int t = threadIdx.x;
    const u16* op = O + (size_t)row * DM;
    float xv[4];
    float s1 = 0.f, s2 = 0.f;
    #pragma unroll
    for (int i = 0; i < 4; i++){
        int idx = i * 256 + t;
        float q = isbf ? bf2f(((const u16*)Qin)[(size_t)row * DM + idx])
                       : ((const float*)Qin)[(size_t)row * DM + idx];
        float x = bf2f(op[idx]) + q;
        xv[i] = x; s1 += x; s2 += x * x;
    }
    #pragma unroll
    for (int off = 32; off; off >>= 1){
        s1 += __shfl_down(s1, off);
        s2 += __shfl_down(s2, off);
    }
    int w = t >> 6, lane = t & 63;
    if (lane == 0){ red[w][0] = s1; red[w][1] = s2; }
    __syncthreads();
    float S1 = red[0][0] + red[1][0] + red[2][0] + red[3][0];
    float S2 = red[0][1] + red[1][1] + red[2][1] + red[3][1];
    float mu  = S1 * (1.0f / DM);
    float var = S2 * (1.0f / DM) - mu * mu;
    float rstd = rsqrtf(var + 1e-5f);
    #pragma unroll
    for (int i = 0; i < 4; i++){
        int idx = i * 256 + t;
        float g = isbf ? bf2f(((const u16*)gamma)[idx]) : ((const float*)gamma)[idx];
        float bb= isbf ? bf2f(((const u16*)beta )[idx]) : ((const float*)beta )[idx];
        float y = (xv[i] - mu) * rstd * g + bb;
        if (isbf) ((u16*)out)[(size_t)row * DM + idx] = f2bf(y);
        else      ((float*)out)[(size_t)row * DM + idx] = y;
    }
}

// ---------------------------------------------------------------------------
extern "C" void kernel_launch(void* const* d_in, const int* in_sizes, int n_in,
                              void* d_out, int out_size, void* d_ws, size_t ws_size,
                              hipStream_t stream){
    (void)in_sizes; (void)n_in; (void)out_size; (void)ws_size;
    const void* inQ = d_in[0];
    const void* inK = d_in[1];
    const void* inV = d_in[2];
    const void* wQ  = d_in[3];
    const void* wK  = d_in[4];
    const void* wV  = d_in[5];
    const void* wO  = d_in[6];
    const void* gma = d_in[7];
    const void* bta = d_in[8];

    int* flag = (int*)d_ws;
    u16* base = (u16*)d_ws + 64;               // 128 B header

    const size_t MB1 = 1024u * 1024u;          // elements
    const size_t M4  = 4u * MB1;
    u16* Qi  = base + 0;                       // bf16 input_Q   (-> ctxp0 later)
    u16* Ki  = base + 1 * M4;                  // bf16 input_K   (-> Vt later)
    u16* Vi  = base + 2 * M4;                  // bf16 input_V   (-> cx later)
    u16* WtQ = base + 3 * M4;                  // W^T each [1024,1024]
    u16* WtK = WtQ + MB1;
    u16* WtV = WtQ + 2 * MB1;
    u16* WtO = WtQ + 3 * MB1;
    u16* Qp  = base + 4 * M4;                  // Q proj         (-> Ob later)
    u16* Kp  = base + 5 * M4;                  // K proj
    u16* Vp  = base + 6 * M4;                  // V proj         (-> ctxp1 later)
    u16* Vt    = Ki;                           // [2][1024][2048]
    u16* ctxp0 = Qi;                           // Qi dead after Q-GEMM
    u16* ctxp1 = Vp;                           // Vp dead after transpose
    u16* cx    = Vi;                           // Vi dead after V-GEMM
    u16* Ob    = Qp;                           // Qp dead after attn

    k_probe<<<1, 64, 0, stream>>>((const u16*)inQ, flag);

    const int nIn = BATCH * SEQ * DM;          // 4M
    k_cvt<<<nIn / (256 * 8), 256, 0, stream>>>(inQ, Qi, flag, nIn);
    k_cvt<<<nIn / (256 * 8), 256, 0, stream>>>(inK, Ki, flag, nIn);
    k_cvt<<<nIn / (256 * 8), 256, 0, stream>>>(inV, Vi, flag, nIn);

    dim3 tt(32, 8);
    k_tcvt<<<dim3(32, 32), tt, 0, stream>>>(wQ, WtQ, flag, 1024, 1024);
    k_tcvt<<<dim3(32, 32), tt, 0, stream>>>(wK, WtK, flag, 1024, 1024);
    k_tcvt<<<dim3(32, 32), tt, 0, stream>>>(wV, WtV, flag, 1024, 1024);
    k_tcvt<<<dim3(32, 32), tt, 0, stream>>>(wO, WtO, flag, 1024, 1024);

    k_gemm128<<<dim3(8, 32), 256, 0, stream>>>(Qi, WtQ, Qp, 4096, 1024, 1024);
    k_gemm128<<<dim3(8, 32), 256, 0, stream>>>(Ki, WtK, Kp, 4096, 1024, 1024);
    k_gemm128<<<dim3(8, 32), 256, 0, stream>>>(Vi, WtV, Vp, 4096, 1024, 1024);

    k_transpose<<<dim3(32, 64, 2), tt, 0, stream>>>(Vp, Vt, 2048, 1024);

    k_attn2<<<256, 1024, 0, stream>>>(Qp, Kp, Vt, ctxp0, ctxp1);

    k_reduce<<<nIn / (256 * 8), 256, 0, stream>>>(ctxp0, ctxp1, cx, nIn);

    k_gemm128<<<dim3(8, 32), 256, 0, stream>>>(cx, WtO, Ob, 4096, 1024, 1024);

    k_ln<<<4096, 256, 0, stream>>>(Ob, inQ, gma, bta, d_out, flag);
}

// Round 4
// 382.498 us; speedup vs baseline: 1.4297x; 1.1558x over previous
//
#include <hip/hip_runtime.h>
#include <cstdint>
#include <cstddef>

#define DM 1024
#define HEADS 16
#define DHEAD 64
#define SEQ 2048
#define BATCH 2

typedef __bf16 bf16x8 __attribute__((ext_vector_type(8)));
typedef float  f32x4  __attribute__((ext_vector_type(4)));
typedef unsigned short u16;
typedef unsigned int u32;
typedef u16 u16x8 __attribute__((ext_vector_type(8)));

__device__ __forceinline__ float bf2f(u16 u){
    union { u32 i; float f; } v; v.i = ((u32)u) << 16; return v.f;
}
__device__ __forceinline__ u16 f2bf(float f){
    union { float f; u32 i; } v; v.f = f;
    u32 r = v.i + 0x7FFF + ((v.i >> 16) & 1);   // RNE
    return (u16)(r >> 16);
}
__device__ __forceinline__ u16 f2bf_rhu(float f){  // cheap round-half-up
    union { float f; u32 i; } v; v.f = f;
    return (u16)((v.i + 0x8000u) >> 16);
}
__device__ __forceinline__ void gload16(const u16* g, u16* l){
    __builtin_amdgcn_global_load_lds(
        (const __attribute__((address_space(1))) u32*)g,
        (__attribute__((address_space(3))) u32*)l, 16, 0, 0);
}

// ---------------------------------------------------------------------------
// Dtype probe: inputs bf16 (flag=1) or fp32 (flag=0)?
// ---------------------------------------------------------------------------
__global__ void k_probe(const u16* __restrict__ q, int* __restrict__ flag){
    if (threadIdx.x == 0 && blockIdx.x == 0){
        int cnt = 0;
        for (int i = 0; i < 256; i += 2){
            int e = (q[i] >> 7) & 0xFF;
            if (e >= 90 && e <= 141) cnt++;
        }
        *flag = (cnt >= 64) ? 1 : 0;
    }
}

// ---------------------------------------------------------------------------
// Convert (fp32|bf16) -> bf16 flat.
// ---------------------------------------------------------------------------
__global__ __launch_bounds__(256) void k_cvt(const void* __restrict__ src,
                                             u16* __restrict__ dst,
                                             const int* __restrict__ flag, int n){
    int i = (blockIdx.x * 256 + threadIdx.x) * 8;
    if (i >= n) return;
    if (*flag){
        *(u16x8*)&dst[i] = *(const u16x8*)((const u16*)src + i);
    } else {
        const float* s = (const float*)src + i;
        u16x8 o;
        #pragma unroll
        for (int j = 0; j < 8; j++) o[j] = f2bf(s[j]);
        *(u16x8*)&dst[i] = o;
    }
}

// ---------------------------------------------------------------------------
// Transpose + convert: dst[c][r] = cvt(src[r][c]).
// ---------------------------------------------------------------------------
__global__ void k_tcvt(const void* __restrict__ src, u16* __restrict__ dst,
                       const int* __restrict__ flag, int R, int C){
    __shared__ u16 tile[32][33];
    bool isbf = (*flag != 0);
    int c0 = blockIdx.x * 32, r0 = blockIdx.y * 32;
    int tx = threadIdx.x, ty = threadIdx.y;     // 32 x 8
    #pragma unroll
    for (int i = 0; i < 32; i += 8){
        size_t idx = (size_t)(r0 + ty + i) * C + c0 + tx;
        tile[ty + i][tx] = isbf ? ((const u16*)src)[idx] : f2bf(((const float*)src)[idx]);
    }
    __syncthreads();
    #pragma unroll
    for (int i = 0; i < 32; i += 8)
        dst[(size_t)(c0 + ty + i) * R + r0 + tx] = tile[tx][ty + i];
}

// ---------------------------------------------------------------------------
// Plain bf16 batched transpose: dst[b][c][r] = src[b][r][c].
// ---------------------------------------------------------------------------
__global__ void k_transpose(const u16* __restrict__ src, u16* __restrict__ dst,
                            int R, int C){
    __shared__ u16 tile[32][33];
    size_t boff = (size_t)blockIdx.z * R * C;
    src += boff; dst += boff;
    int c0 = blockIdx.x * 32, r0 = blockIdx.y * 32;
    int tx = threadIdx.x, ty = threadIdx.y;
    #pragma unroll
    for (int i = 0; i < 32; i += 8)
        tile[ty + i][tx] = src[(size_t)(r0 + ty + i) * C + c0 + tx];
    __syncthreads();
    #pragma unroll
    for (int i = 0; i < 32; i += 8)
        dst[(size_t)(c0 + ty + i) * R + r0 + tx] = tile[tx][ty + i];
}

// ---------------------------------------------------------------------------
// C[M,N] = A[M,K]*Bt[N,K]^T.  128(M)x64(N) tile, BK=32, 256 thr = 4 waves,
// each wave a 64x32 quadrant. global_load_lds(16B) staging into XOR-swizzled
// LDS (wave-uniform dest constraint). Grid 512 blocks = 2/CU.
// ---------------------------------------------------------------------------
__global__ __launch_bounds__(256, 2) void k_gemm2(const u16* __restrict__ A,
                                                  const u16* __restrict__ Bt,
                                                  u16* __restrict__ C,
                                                  int M, int N, int K){
    __shared__ u16 lsA[128 * 32];   // row r, logical 16B-chunk c at r*4 + (c^(r&3))
    __shared__ u16 lsB[64 * 32];
    int m0 = blockIdx.y * 128, n0 = blockIdx.x * 64;
    int t = threadIdx.x, lane = t & 63, w = t >> 6;
    int l15 = lane & 15, quad = lane >> 4;
    int wm = (w & 1) * 64, wn = (w >> 1) * 32;
    // staging: wave w -> A rows 32w..32w+31 (2 instrs), B rows 16w..16w+15 (1)
    int rA0 = 32 * w + (lane >> 2);
    int rA1 = rA0 + 16;
    int rB  = 16 * w + (lane >> 2);
    int cA0 = (lane & 3) ^ (rA0 & 3);
    int cA1 = (lane & 3) ^ (rA1 & 3);
    int cB  = (lane & 3) ^ (rB  & 3);
    u16* dA0 = &lsA[(32 * w) * 32];       // wave-uniform LDS bases
    u16* dA1 = &lsA[(32 * w + 16) * 32];
    u16* dB  = &lsB[(16 * w) * 32];
    f32x4 acc[4][2] = {};
    for (int k0 = 0; k0 < K; k0 += 32){
        __syncthreads();
        gload16(&A [(size_t)(m0 + rA0) * K + k0 + cA0 * 8], dA0);
        gload16(&A [(size_t)(m0 + rA1) * K + k0 + cA1 * 8], dA1);
        gload16(&Bt[(size_t)(n0 + rB ) * K + k0 + cB  * 8], dB);
        __syncthreads();
        bf16x8 af[4], bfr[2];
        #pragma unroll
        for (int i = 0; i < 4; i++){
            int row = wm + i * 16 + l15;
            af[i] = *(const bf16x8*)&lsA[row * 32 + ((quad ^ (row & 3)) * 8)];
        }
        #pragma unroll
        for (int j = 0; j < 2; j++){
            int row = wn + j * 16 + l15;
            bfr[j] = *(const bf16x8*)&lsB[row * 32 + ((quad ^ (row & 3)) * 8)];
        }
        #pragma unroll
        for (int i = 0; i < 4; i++)
            #pragma unroll
            for (int j = 0; j < 2; j++)
                acc[i][j] = __builtin_amdgcn_mfma_f32_16x16x32_bf16(af[i], bfr[j], acc[i][j], 0, 0, 0);
    }
    #pragma unroll
    for (int i = 0; i < 4; i++)
        #pragma unroll
        for (int j = 0; j < 2; j++)
            #pragma unroll
            for (int r = 0; r < 4; r++){
                int m = m0 + wm + i * 16 + quad * 4 + r;
                int n = n0 + wn + j * 16 + l15;
                C[(size_t)m * N + n] = f2bf(acc[i][j][r]);
            }
}

// ---------------------------------------------------------------------------
// Fused attention v3, softmax over HEADS. 256 blocks: bid&3 -> (b, k-chunk);
// bid>>2 -> 32-row q-tile. 16 waves (wave h = head h). BK=64, double-buffered
// e/P exchange so PV(i) overlaps score+exp(i+1); 2 barriers/iter, 16 iters.
// e computed (exp2, no max — scores bounded) by owning wave; softmax phase
// only sums + scales in place (paired u32).
// ---------------------------------------------------------------------------
__global__ __launch_bounds__(1024, 4) void k_attn3(const u16* __restrict__ Qp,
                                                   const u16* __restrict__ Kp,
                                                   const u16* __restrict__ Vt,
                                                   u16* __restrict__ ctxp0,
                                                   u16* __restrict__ ctxp1){
    __shared__ u16 ebuf[2][16][32][72];   // 144 KB; stride 72 u16 = 144 B (16B-aligned)
    int bid = blockIdx.x;
    int b = bid & 1, chunk = (bid >> 1) & 1;
    int q0 = (bid >> 2) * 32;
    int t = threadIdx.x;
    int h = t >> 6, lane = t & 63, l15 = lane & 15, quad = lane >> 4;
    u16* outp = chunk ? ctxp1 : ctxp0;
    const float cexp = 0.125f * 1.44269504f;   // scores/8, exp2 domain

    bf16x8 qf[2][2];
    #pragma unroll
    for (int sub = 0; sub < 2; sub++)
        #pragma unroll
        for (int ch = 0; ch < 2; ch++)
            qf[sub][ch] = *(const bf16x8*)&Qp[((size_t)(b * SEQ + q0 + sub * 16 + l15)) * DM
                                             + h * DHEAD + ch * 32 + quad * 8];

    f32x4 oacc[2][4] = {};
    int rq = t >> 5, rk2 = (t & 31) * 2;
    int kbeg = chunk * 1024;

    auto score_phase = [&](int it){
        int k0 = kbeg + it * 64, buf = it & 1;
        #pragma unroll
        for (int kt = 0; kt < 4; kt++){
            const u16* kb = Kp + ((size_t)(b * SEQ + k0 + kt * 16 + l15)) * DM + h * DHEAD + quad * 8;
            bf16x8 kf0 = *(const bf16x8*)(kb);
            bf16x8 kf1 = *(const bf16x8*)(kb + 32);
            #pragma unroll
            for (int sub = 0; sub < 2; sub++){
                f32x4 sc = {};
                sc = __builtin_amdgcn_mfma_f32_16x16x32_bf16(qf[sub][0], kf0, sc, 0, 0, 0);
                sc = __builtin_amdgcn_mfma_f32_16x16x32_bf16(qf[sub][1], kf1, sc, 0, 0, 0);
                #pragma unroll
                for (int r = 0; r < 4; r++)
                    ebuf[buf][h][sub * 16 + quad * 4 + r][kt * 16 + l15] =
                        f2bf_rhu(exp2f(sc[r] * cexp));
            }
        }
    };

    score_phase(0);
    for (int it = 0; it < 16; it++){
        int buf = it & 1;
        __syncthreads();                       // B1: e(it) complete
        {   // softmax across heads, in place; thread owns (rq, k=rk2..rk2+1)
            u32 ev[16];
            float s0 = 0.f, s1 = 0.f;
            #pragma unroll
            for (int hh = 0; hh < 16; hh++){
                u32 u = *(const u32*)&ebuf[buf][hh][rq][rk2];
                ev[hh] = u;
                union { u32 i; float f; } lo, hi;
                lo.i = u << 16; hi.i = u & 0xFFFF0000u;
                s0 += lo.f; s1 += hi.f;
            }
            float r0 = __builtin_amdgcn_rcpf(s0);
            float r1 = __builtin_amdgcn_rcpf(s1);
            #pragma unroll
            for (int hh = 0; hh < 16; hh++){
                union { u32 i; float f; } lo, hi, p0, p1;
                lo.i = ev[hh] << 16; hi.i = ev[hh] & 0xFFFF0000u;
                p0.f = lo.f * r0; p1.f = hi.f * r1;
                *(u32*)&ebuf[buf][hh][rq][rk2] =
                    ((p0.i + 0x8000u) >> 16) | ((p1.i + 0x8000u) & 0xFFFF0000u);
            }
        }
        __syncthreads();                       // B2: P(it) ready
        // PV(it) — overlapped with score_phase(it+1) writing the other buffer
        int k0 = kbeg + it * 64;
        #pragma unroll
        for (int half = 0; half < 2; half++){
            bf16x8 pa0 = *(const bf16x8*)&ebuf[buf][h][     l15][half * 32 + quad * 8];
            bf16x8 pa1 = *(const bf16x8*)&ebuf[buf][h][16 + l15][half * 32 + quad * 8];
            #pragma unroll
            for (int vt = 0; vt < 4; vt++){
                bf16x8 vf = *(const bf16x8*)&Vt[((size_t)b * DM + h * DHEAD + vt * 16 + l15) * SEQ
                                                + k0 + half * 32 + quad * 8];
                oacc[0][vt] = __builtin_amdgcn_mfma_f32_16x16x32_bf16(pa0, vf, oacc[0][vt], 0, 0, 0);
                oacc[1][vt] = __builtin_amdgcn_mfma_f32_16x16x32_bf16(pa1, vf, oacc[1][vt], 0, 0, 0);
            }
        }
        if (it < 15) score_phase(it + 1);
    }
    #pragma unroll
    for (int sub = 0; sub < 2; sub++)
        #pragma unroll
        for (int vt = 0; vt < 4; vt++)
            #pragma unroll
            for (int r = 0; r < 4; r++){
                int q = q0 + sub * 16 + quad * 4 + r;
                int n = h * DHEAD + vt * 16 + l15;
                outp[((size_t)b * SEQ + q) * DM + n] = f2bf(oacc[sub][vt][r]);
            }
}

// ---------------------------------------------------------------------------
// cx = ctxp0 + ctxp1 (bf16)
// ---------------------------------------------------------------------------
__global__ __launch_bounds__(256) void k_reduce(const u16* __restrict__ a,
                                                const u16* __restrict__ b,
                                                u16* __restrict__ dst, int n){
    int i = (blockIdx.x * 256 + threadIdx.x) * 8;
    if (i >= n) return;
    u16x8 x = *(const u16x8*)&a[i];
    u16x8 y = *(const u16x8*)&b[i];
    u16x8 o;
    #pragma unroll
    for (int j = 0; j < 8; j++) o[j] = f2bf(bf2f(x[j]) + bf2f(y[j]));
    *(u16x8*)&dst[i] = o;
}

// ---------------------------------------------------------------------------
// Residual + LayerNorm over last dim (1024). One block per row.
// ---------------------------------------------------------------------------
__global__ __launch_bounds__(256) void k_ln(const u16* __restrict__ O,
                                            const void* __restrict__ Qin,
                                            const void* __restrict__ gamma,
                                            const void* __restrict__ beta,
                                            void* __restrict__ out,
                                            const int* __restrict__ flag){
    __shared__ float red[4][2];
    bool isbf = (*flag != 0);
    int row = blockIdx.x;
    int t = threadIdx.x;
    const u16* op = O + (size_t)row * DM;
    float xv[4];
    float s1 = 0.f, s2 = 0.f;
    #pragma unroll
    for (int i = 0; i < 4; i++){
        int idx = i * 256 + t;
        float q = isbf ? bf2f(((const u16*)Qin)[(size_t)row * DM + idx])
                       : ((const float*)Qin)[(size_t)row * DM + idx];
        float x = bf2f(op[idx]) + q;
        xv[i] = x; s1 += x; s2 += x * x;
    }
    #pragma unroll
    for (int off = 32; off; off >>= 1){
        s1 += __shfl_down(s1, off);
        s2 += __shfl_down(s2, off);
    }
    int w = t >> 6, lane = t & 63;
    if (lane == 0){ red[w][0] = s1; red[w][1] = s2; }
    __syncthreads();
    float S1 = red[0][0] + red[1][0] + red[2][0] + red[3][0];
    float S2 = red[0][1] + red[1][1] + red[2][1] + red[3][1];
    float mu  = S1 * (1.0f / DM);
    float var = S2 * (1.0f / DM) - mu * mu;
    float rstd = rsqrtf(var + 1e-5f);
    #pragma unroll
    for (int i = 0; i < 4; i++){
        int idx = i * 256 + t;
        float g = isbf ? bf2f(((const u16*)gamma)[idx]) : ((const float*)gamma)[idx];
        float bb= isbf ? bf2f(((const u16*)beta )[idx]) : ((const float*)beta )[idx];
        float y = (xv[i] - mu) * rstd * g + bb;
        if (isbf) ((u16*)out)[(size_t)row * DM + idx] = f2bf(y);
        else      ((float*)out)[(size_t)row * DM + idx] = y;
    }
}

// ---------------------------------------------------------------------------
extern "C" void kernel_launch(void* const* d_in, const int* in_sizes, int n_in,
                              void* d_out, int out_size, void* d_ws, size_t ws_size,
                              hipStream_t stream){
    (void)in_sizes; (void)n_in; (void)out_size; (void)ws_size;
    const void* inQ = d_in[0];
    const void* inK = d_in[1];
    const void* inV = d_in[2];
    const void* wQ  = d_in[3];
    const void* wK  = d_in[4];
    const void* wV  = d_in[5];
    const void* wO  = d_in[6];
    const void* gma = d_in[7];
    const void* bta = d_in[8];

    int* flag = (int*)d_ws;
    u16* base = (u16*)d_ws + 64;               // 128 B header

    const size_t MB1 = 1024u * 1024u;          // elements
    const size_t M4  = 4u * MB1;
    u16* Qi  = base + 0;                       // bf16 input_Q   (-> ctxp0 later)
    u16* Ki  = base + 1 * M4;                  // bf16 input_K   (-> Vt later)
    u16* Vi  = base + 2 * M4;                  // bf16 input_V   (-> cx later)
    u16* WtQ = base + 3 * M4;                  // W^T each [1024,1024]
    u16* WtK = WtQ + MB1;
    u16* WtV = WtQ + 2 * MB1;
    u16* WtO = WtQ + 3 * MB1;
    u16* Qp  = base + 4 * M4;                  // Q proj         (-> Ob later)
    u16* Kp  = base + 5 * M4;                  // K proj
    u16* Vp  = base + 6 * M4;                  // V proj         (-> ctxp1 later)
    u16* Vt    = Ki;                           // [2][1024][2048]
    u16* ctxp0 = Qi;
    u16* ctxp1 = Vp;
    u16* cx    = Vi;
    u16* Ob    = Qp;

    k_probe<<<1, 64, 0, stream>>>((const u16*)inQ, flag);

    const int nIn = BATCH * SEQ * DM;          // 4M
    k_cvt<<<nIn / (256 * 8), 256, 0, stream>>>(inQ, Qi, flag, nIn);
    k_cvt<<<nIn / (256 * 8), 256, 0, stream>>>(inK, Ki, flag, nIn);
    k_cvt<<<nIn / (256 * 8), 256, 0, stream>>>(inV, Vi, flag, nIn);

    dim3 tt(32, 8);
    k_tcvt<<<dim3(32, 32), tt, 0, stream>>>(wQ, WtQ, flag, 1024, 1024);
    k_tcvt<<<dim3(32, 32), tt, 0, stream>>>(wK, WtK, flag, 1024, 1024);
    k_tcvt<<<dim3(32, 32), tt, 0, stream>>>(wV, WtV, flag, 1024, 1024);
    k_tcvt<<<dim3(32, 32), tt, 0, stream>>>(wO, WtO, flag, 1024, 1024);

    k_gemm2<<<dim3(16, 32), 256, 0, stream>>>(Qi, WtQ, Qp, 4096, 1024, 1024);
    k_gemm2<<<dim3(16, 32), 256, 0, stream>>>(Ki, WtK, Kp, 4096, 1024, 1024);
    k_gemm2<<<dim3(16, 32), 256, 0, stream>>>(Vi, WtV, Vp, 4096, 1024, 1024);

    k_transpose<<<dim3(32, 64, 2), tt, 0, stream>>>(Vp, Vt, 2048, 1024);

    k_attn3<<<256, 1024, 0, stream>>>(Qp, Kp, Vt, ctxp0, ctxp1);

    k_reduce<<<nIn / (256 * 8), 256, 0, stream>>>(ctxp0, ctxp1, cx, nIn);

    k_gemm2<<<dim3(16, 32), 256, 0, stream>>>(cx, WtO, Ob, 4096, 1024, 1024);

    k_ln<<<4096, 256, 0, stream>>>(Ob, inQ, gma, bta, d_out, flag);
}

// Round 5
// 341.066 us; speedup vs baseline: 1.6034x; 1.1215x over previous
//
#include <hip/hip_runtime.h>
#include <cstdint>
#include <cstddef>

#define DM 1024
#define HEADS 16
#define DHEAD 64
#define SEQ 2048
#define BATCH 2

typedef __bf16 bf16x8 __attribute__((ext_vector_type(8)));
typedef float  f32x4  __attribute__((ext_vector_type(4)));
typedef unsigned short u16;
typedef unsigned int u32;
typedef u16 u16x8 __attribute__((ext_vector_type(8)));
typedef u16 u16x4 __attribute__((ext_vector_type(4)));

__device__ __forceinline__ float bf2f(u16 u){
    union { u32 i; float f; } v; v.i = ((u32)u) << 16; return v.f;
}
__device__ __forceinline__ u16 f2bf(float f){
    union { float f; u32 i; } v; v.f = f;
    u32 r = v.i + 0x7FFF + ((v.i >> 16) & 1);   // RNE
    return (u16)(r >> 16);
}
__device__ __forceinline__ u16 f2bf_rhu(float f){  // cheap round-half-up (positive)
    union { float f; u32 i; } v; v.f = f;
    return (u16)((v.i + 0x8000u) >> 16);
}
__device__ __forceinline__ void gload16(const u16* g, u16* l){
    __builtin_amdgcn_global_load_lds(
        (const __attribute__((address_space(1))) u32*)g,
        (__attribute__((address_space(3))) u32*)l, 16, 0, 0);
}

// ---------------------------------------------------------------------------
// Dtype probe: inputs bf16 (flag=1) or fp32 (flag=0)?
// ---------------------------------------------------------------------------
__global__ void k_probe(const u16* __restrict__ q, int* __restrict__ flag){
    if (threadIdx.x == 0 && blockIdx.x == 0){
        int cnt = 0;
        for (int i = 0; i < 256; i += 2){
            int e = (q[i] >> 7) & 0xFF;
            if (e >= 90 && e <= 141) cnt++;
        }
        *flag = (cnt >= 64) ? 1 : 0;
    }
}

// ---------------------------------------------------------------------------
// Convert 3 tensors (fp32|bf16) -> bf16, dst contiguous slots. z = tensor.
// ---------------------------------------------------------------------------
__global__ __launch_bounds__(256) void k_cvt3(const void* __restrict__ s0,
                                              const void* __restrict__ s1,
                                              const void* __restrict__ s2,
                                              u16* __restrict__ dstbase,
                                              const int* __restrict__ flag, int n){
    int z = blockIdx.y;
    const void* src = (z == 0) ? s0 : ((z == 1) ? s1 : s2);
    u16* dst = dstbase + (size_t)z * n;
    int i = (blockIdx.x * 256 + threadIdx.x) * 8;
    if (i >= n) return;
    if (*flag){
        *(u16x8*)&dst[i] = *(const u16x8*)((const u16*)src + i);
    } else {
        const float* s = (const float*)src + i;
        u16x8 o;
        #pragma unroll
        for (int j = 0; j < 8; j++) o[j] = f2bf(s[j]);
        *(u16x8*)&dst[i] = o;
    }
}

// ---------------------------------------------------------------------------
// Transpose+convert 4 weight matrices: dst_z[c][r] = cvt(src_z[r][c]).
// ---------------------------------------------------------------------------
__global__ void k_tcvt4(const void* __restrict__ w0, const void* __restrict__ w1,
                        const void* __restrict__ w2, const void* __restrict__ w3,
                        u16* __restrict__ dstbase,
                        const int* __restrict__ flag, int R, int C){
    __shared__ u16 tile[32][33];
    int z = blockIdx.z;
    const void* src = (z == 0) ? w0 : ((z == 1) ? w1 : ((z == 2) ? w2 : w3));
    u16* dst = dstbase + (size_t)z * R * C;
    bool isbf = (*flag != 0);
    int c0 = blockIdx.x * 32, r0 = blockIdx.y * 32;
    int tx = threadIdx.x, ty = threadIdx.y;     // 32 x 8
    #pragma unroll
    for (int i = 0; i < 32; i += 8){
        size_t idx = (size_t)(r0 + ty + i) * C + c0 + tx;
        tile[ty + i][tx] = isbf ? ((const u16*)src)[idx] : f2bf(((const float*)src)[idx]);
    }
    __syncthreads();
    #pragma unroll
    for (int i = 0; i < 32; i += 8)
        dst[(size_t)(c0 + ty + i) * R + r0 + tx] = tile[tx][ty + i];
}

// ---------------------------------------------------------------------------
// Plain bf16 batched transpose: dst[b][c][r] = src[b][r][c].
// ---------------------------------------------------------------------------
__global__ void k_transpose(const u16* __restrict__ src, u16* __restrict__ dst,
                            int R, int C){
    __shared__ u16 tile[32][33];
    size_t boff = (size_t)blockIdx.z * R * C;
    src += boff; dst += boff;
    int c0 = blockIdx.x * 32, r0 = blockIdx.y * 32;
    int tx = threadIdx.x, ty = threadIdx.y;
    #pragma unroll
    for (int i = 0; i < 32; i += 8)
        tile[ty + i][tx] = src[(size_t)(r0 + ty + i) * C + c0 + tx];
    __syncthreads();
    #pragma unroll
    for (int i = 0; i < 32; i += 8)
        dst[(size_t)(c0 + ty + i) * R + r0 + tx] = tile[tx][ty + i];
}

// ---------------------------------------------------------------------------
// C[M,N] = A[M,K]*Bt[N,K]^T, z-batched (A,Bt,C offset by z*stride).
// 128(M)x64(N) tile, BK=32, 256 thr = 4 waves, wave = 64x32 quadrant,
// global_load_lds(16B) into XOR-swizzled LDS.
// ---------------------------------------------------------------------------
__global__ __launch_bounds__(256, 2) void k_gemm2z(const u16* __restrict__ A0,
                                                   const u16* __restrict__ Bt0,
                                                   u16* __restrict__ C0,
                                                   size_t strA, size_t strB, size_t strC,
                                                   int M, int N, int K){
    __shared__ u16 lsA[128 * 32];
    __shared__ u16 lsB[64 * 32];
    int z = blockIdx.z;
    const u16* A  = A0  + strA * z;
    const u16* Bt = Bt0 + strB * z;
    u16* C = C0 + strC * z;
    int m0 = blockIdx.y * 128, n0 = blockIdx.x * 64;
    int t = threadIdx.x, lane = t & 63, w = t >> 6;
    int l15 = lane & 15, quad = lane >> 4;
    int wm = (w & 1) * 64, wn = (w >> 1) * 32;
    int rA0 = 32 * w + (lane >> 2);
    int rA1 = rA0 + 16;
    int rB  = 16 * w + (lane >> 2);
    int cA0 = (lane & 3) ^ (rA0 & 3);
    int cA1 = (lane & 3) ^ (rA1 & 3);
    int cB  = (lane & 3) ^ (rB  & 3);
    u16* dA0 = &lsA[(32 * w) * 32];
    u16* dA1 = &lsA[(32 * w + 16) * 32];
    u16* dB  = &lsB[(16 * w) * 32];
    f32x4 acc[4][2] = {};
    for (int k0 = 0; k0 < K; k0 += 32){
        __syncthreads();
        gload16(&A [(size_t)(m0 + rA0) * K + k0 + cA0 * 8], dA0);
        gload16(&A [(size_t)(m0 + rA1) * K + k0 + cA1 * 8], dA1);
        gload16(&Bt[(size_t)(n0 + rB ) * K + k0 + cB  * 8], dB);
        __syncthreads();
        bf16x8 af[4], bfr[2];
        #pragma unroll
        for (int i = 0; i < 4; i++){
            int row = wm + i * 16 + l15;
            af[i] = *(const bf16x8*)&lsA[row * 32 + ((quad ^ (row & 3)) * 8)];
        }
        #pragma unroll
        for (int j = 0; j < 2; j++){
            int row = wn + j * 16 + l15;
            bfr[j] = *(const bf16x8*)&lsB[row * 32 + ((quad ^ (row & 3)) * 8)];
        }
        #pragma unroll
        for (int i = 0; i < 4; i++)
            #pragma unroll
            for (int j = 0; j < 2; j++)
                acc[i][j] = __builtin_amdgcn_mfma_f32_16x16x32_bf16(af[i], bfr[j], acc[i][j], 0, 0, 0);
    }
    #pragma unroll
    for (int i = 0; i < 4; i++)
        #pragma unroll
        for (int j = 0; j < 2; j++)
            #pragma unroll
            for (int r = 0; r < 4; r++){
                int m = m0 + wm + i * 16 + quad * 4 + r;
                int n = n0 + wn + j * 16 + l15;
                C[(size_t)m * N + n] = f2bf(acc[i][j][r]);
            }
}

// ---------------------------------------------------------------------------
// Fused attention v4, softmax over HEADS. qtile=64, ktile=32, nchunks k-split.
// grid = 32 qtiles * 2 b * nch chunks; combo = bid & (2*nch-1).
// 16 waves (wave h = head h), each wave 64q x 64v. Double-buffered e/P LDS.
// ---------------------------------------------------------------------------
__global__ __launch_bounds__(1024, 4) void k_attn4(const u16* __restrict__ Qp,
                                                   const u16* __restrict__ Kp,
                                                   const u16* __restrict__ Vt,
                                                   u16* __restrict__ c0,
                                                   u16* __restrict__ c1,
                                                   u16* __restrict__ c2,
                                                   u16* __restrict__ c3,
                                                   int qtShift, int iters){
    __shared__ u16 ebuf[2][16][64][36];   // 144 KB; row stride 72 B (8B-aligned)
    int bid = blockIdx.x;
    int combo = bid & ((1 << qtShift) - 1);
    int b = combo & 1, chunk = combo >> 1;
    int q0 = (bid >> qtShift) * 64;
    int t = threadIdx.x;
    int h = t >> 6, lane = t & 63, l15 = lane & 15, quad = lane >> 4;
    u16* outp = (chunk == 0) ? c0 : ((chunk == 1) ? c1 : ((chunk == 2) ? c2 : c3));
    const float cexp = 0.125f * 1.44269504f;
    int kbeg = chunk * (iters << 5);

    bf16x8 qf[4][2];
    #pragma unroll
    for (int sub = 0; sub < 4; sub++)
        #pragma unroll
        for (int ch = 0; ch < 2; ch++)
            qf[sub][ch] = *(const bf16x8*)&Qp[((size_t)(b * SEQ + q0 + sub * 16 + l15)) * DM
                                             + h * DHEAD + ch * 32 + quad * 8];

    f32x4 oacc[4][4] = {};
    int sq = t >> 4, sku = (t & 15) * 2;   // softmax owns (q=sq, k=sku..sku+1)

    auto score_phase = [&](int it){
        int k0 = kbeg + (it << 5), bf = it & 1;
        #pragma unroll
        for (int kt = 0; kt < 2; kt++){
            const u16* kb = Kp + ((size_t)(b * SEQ + k0 + kt * 16 + l15)) * DM + h * DHEAD + quad * 8;
            bf16x8 kf0 = *(const bf16x8*)(kb);
            bf16x8 kf1 = *(const bf16x8*)(kb + 32);
            #pragma unroll
            for (int sub = 0; sub < 4; sub++){
                f32x4 sc = {};
                sc = __builtin_amdgcn_mfma_f32_16x16x32_bf16(qf[sub][0], kf0, sc, 0, 0, 0);
                sc = __builtin_amdgcn_mfma_f32_16x16x32_bf16(qf[sub][1], kf1, sc, 0, 0, 0);
                #pragma unroll
                for (int r = 0; r < 4; r++)
                    ebuf[bf][h][sub * 16 + quad * 4 + r][kt * 16 + l15] =
                        f2bf_rhu(exp2f(sc[r] * cexp));
            }
        }
    };

    score_phase(0);
    for (int it = 0; it < iters; it++){
        int bf = it & 1;
        __syncthreads();                       // B1: e(it) complete
        {   // softmax across 16 heads, in place (u32 = 2 packed bf16)
            u32 ev[16];
            float s0 = 0.f, s1 = 0.f;
            #pragma unroll
            for (int hh = 0; hh < 16; hh++){
                u32 u = *(const u32*)&ebuf[bf][hh][sq][sku];
                ev[hh] = u;
                union { u32 i; float f; } lo, hi;
                lo.i = u << 16; hi.i = u & 0xFFFF0000u;
                s0 += lo.f; s1 += hi.f;
            }
            float r0 = __builtin_amdgcn_rcpf(s0);
            float r1 = __builtin_amdgcn_rcpf(s1);
            #pragma unroll
            for (int hh = 0; hh < 16; hh++){
                union { u32 i; float f; } lo, hi, p0, p1;
                lo.i = ev[hh] << 16; hi.i = ev[hh] & 0xFFFF0000u;
                p0.f = lo.f * r0; p1.f = hi.f * r1;
                *(u32*)&ebuf[bf][hh][sq][sku] =
                    ((p0.i + 0x8000u) >> 16) | ((p1.i + 0x8000u) & 0xFFFF0000u);
            }
        }
        __syncthreads();                       // B2: P(it) ready
        int k0 = kbeg + (it << 5);
        bf16x8 pa[4];
        #pragma unroll
        for (int sub = 0; sub < 4; sub++){
            const u16* pp = &ebuf[bf][h][sub * 16 + l15][quad * 8];
            union { bf16x8 v; u16x4 q[2]; } pu;
            pu.q[0] = *(const u16x4*)pp;
            pu.q[1] = *(const u16x4*)(pp + 4);
            pa[sub] = pu.v;
        }
        #pragma unroll
        for (int vt = 0; vt < 4; vt++){
            bf16x8 vf = *(const bf16x8*)&Vt[((size_t)b * DM + h * DHEAD + vt * 16 + l15) * SEQ
                                            + k0 + quad * 8];
            #pragma unroll
            for (int sub = 0; sub < 4; sub++)
                oacc[sub][vt] = __builtin_amdgcn_mfma_f32_16x16x32_bf16(pa[sub], vf, oacc[sub][vt], 0, 0, 0);
        }
        if (it + 1 < iters) score_phase(it + 1);
    }
    #pragma unroll
    for (int sub = 0; sub < 4; sub++)
        #pragma unroll
        for (int vt = 0; vt < 4; vt++)
            #pragma unroll
            for (int r = 0; r < 4; r++){
                int q = q0 + sub * 16 + quad * 4 + r;
                int n = h * DHEAD + vt * 16 + l15;
                outp[((size_t)b * SEQ + q) * DM + n] = f2bf(oacc[sub][vt][r]);
            }
}

// ---------------------------------------------------------------------------
// dst = c0+c1(+c2+c3) (bf16). dst may alias c0 (same-index load-then-store).
// ---------------------------------------------------------------------------
__global__ __launch_bounds__(256) void k_reduce(const u16* __restrict__ a,
                                                const u16* __restrict__ b,
                                                const u16* __restrict__ c,
                                                const u16* __restrict__ d,
                                                u16* __restrict__ dst, int n, int nch){
    int i = (blockIdx.x * 256 + threadIdx.x) * 8;
    if (i >= n) return;
    u16x8 x = *(const u16x8*)&a[i];
    u16x8 y = *(const u16x8*)&b[i];
    u16x8 o;
    if (nch == 4){
        u16x8 zc = *(const u16x8*)&c[i];
        u16x8 zd = *(const u16x8*)&d[i];
        #pragma unroll
        for (int j = 0; j < 8; j++)
            o[j] = f2bf((bf2f(x[j]) + bf2f(y[j])) + (bf2f(zc[j]) + bf2f(zd[j])));
    } else {
        #pragma unroll
        for (int j = 0; j < 8; j++) o[j] = f2bf(bf2f(x[j]) + bf2f(y[j]));
    }
    *(u16x8*)&dst[i] = o;
}

// ---------------------------------------------------------------------------
// Residual + LayerNorm over last dim (1024). One block per row.
// ---------------------------------------------------------------------------
__global__ __launch_bounds__(256) void k_ln(const u16* __restrict__ O,
                                            const void* __restrict__ Qin,
                                            const void* __restrict__ gamma,
                                            const void* __restrict__ beta,
                                            void* __restrict__ out,
                                            const int* __restrict__ flag){
    __shared__ float red[4][2];
    bool isbf = (*flag != 0);
    int row = blockIdx.x;
    int t = threadIdx.x;
    const u16* op = O + (size_t)row * DM;
    float xv[4];
    float s1 = 0.f, s2 = 0.f;
    #pragma unroll
    for (int i = 0; i < 4; i++){
        int idx = i * 256 + t;
        float q = isbf ? bf2f(((const u16*)Qin)[(size_t)row * DM + idx])
                       : ((const float*)Qin)[(size_t)row * DM + idx];
        float x = bf2f(op[idx]) + q;
        xv[i] = x; s1 += x; s2 += x * x;
    }
    #pragma unroll
    for (int off = 32; off; off >>= 1){
        s1 += __shfl_down(s1, off);
        s2 += __shfl_down(s2, off);
    }
    int w = t >> 6, lane = t & 63;
    if (lane == 0){ red[w][0] = s1; red[w][1] = s2; }
    __syncthreads();
    float S1 = red[0][0] + red[1][0] + red[2][0] + red[3][0];
    float S2 = red[0][1] + red[1][1] + red[2][1] + red[3][1];
    float mu  = S1 * (1.0f / DM);
    float var = S2 * (1.0f / DM) - mu * mu;
    float rstd = rsqrtf(var + 1e-5f);
    #pragma unroll
    for (int i = 0; i < 4; i++){
        int idx = i * 256 + t;
        float g = isbf ? bf2f(((const u16*)gamma)[idx]) : ((const float*)gamma)[idx];
        float bb= isbf ? bf2f(((const u16*)beta )[idx]) : ((const float*)beta )[idx];
        float y = (xv[i] - mu) * rstd * g + bb;
        if (isbf) ((u16*)out)[(size_t)row * DM + idx] = f2bf(y);
        else      ((float*)out)[(size_t)row * DM + idx] = y;
    }
}

// ---------------------------------------------------------------------------
extern "C" void kernel_launch(void* const* d_in, const int* in_sizes, int n_in,
                              void* d_out, int out_size, void* d_ws, size_t ws_size,
                              hipStream_t stream){
    (void)in_sizes; (void)n_in; (void)out_size;
    const void* inQ = d_in[0];
    const void* inK = d_in[1];
    const void* inV = d_in[2];
    const void* wQ  = d_in[3];
    const void* wK  = d_in[4];
    const void* wV  = d_in[5];
    const void* wO  = d_in[6];
    const void* gma = d_in[7];
    const void* bta = d_in[8];

    int* flag = (int*)d_ws;
    u16* base = (u16*)d_ws + 64;               // 128 B header

    const size_t MB1 = 1024u * 1024u;          // elements
    const size_t M4  = 4u * MB1;
    u16* Qi  = base + 0;                       // slot0: bf16 Q input -> ctxp0/cx
    u16* Ki  = base + 1 * M4;                  // slot1: bf16 K input -> Vt
    u16* Vi  = base + 2 * M4;                  // slot2: bf16 V input -> ctxp2
    u16* WtQ = base + 3 * M4;                  // slot3: 4 x W^T [1024,1024]
    u16* WtO = WtQ + 3 * MB1;
    u16* Qp  = base + 4 * M4;                  // slot4: Q proj -> Ob
    u16* Kp  = base + 5 * M4;                  // slot5: K proj
    u16* Vp  = base + 6 * M4;                  // slot6: V proj -> ctxp1
    u16* ext = base + 7 * M4;                  // slot7: ctxp3 (if ws allows)
    u16* Vt    = Ki;
    u16* ctxp0 = Qi;
    u16* ctxp1 = Vp;
    u16* ctxp2 = Vi;

    // nchunks=4 needs 8 slots (64 MB + header); fall back to 2 chunks otherwise
    size_t need4 = 128 + 8 * M4 * sizeof(u16);
    int nch = (ws_size >= need4) ? 4 : 2;
    u16* ctxp3 = (nch == 4) ? ext : ctxp2;     // dummy when nch==2 (never selected)
    int qtShift = (nch == 4) ? 3 : 2;
    int iters   = (nch == 4) ? 16 : 32;        // keys per chunk / 32
    int ablocks = 32 * 2 * nch;                // qtiles * batches * chunks

    k_probe<<<1, 64, 0, stream>>>((const u16*)inQ, flag);

    const int nIn = BATCH * SEQ * DM;          // 4M
    k_cvt3<<<dim3(nIn / 2048, 3), 256, 0, stream>>>(inQ, inK, inV, base, flag, nIn);

    k_tcvt4<<<dim3(32, 32, 4), dim3(32, 8), 0, stream>>>(wQ, wK, wV, wO, WtQ, flag, 1024, 1024);

    // Q/K/V projections in one dispatch (z selects A/Bt/C triple)
    k_gemm2z<<<dim3(16, 32, 3), 256, 0, stream>>>(Qi, WtQ, Qp, M4, MB1, M4, 4096, 1024, 1024);

    k_transpose<<<dim3(32, 64, 2), dim3(32, 8), 0, stream>>>(Vp, Vt, 2048, 1024);

    k_attn4<<<ablocks, 1024, 0, stream>>>(Qp, Kp, Vt, ctxp0, ctxp1, ctxp2, ctxp3,
                                          qtShift, iters);

    k_reduce<<<nIn / 2048, 256, 0, stream>>>(ctxp0, ctxp1, ctxp2, ctxp3, ctxp0, nIn, nch);

    k_gemm2z<<<dim3(16, 32, 1), 256, 0, stream>>>(ctxp0, WtO, Qp, 0, 0, 0, 4096, 1024, 1024);

    k_ln<<<4096, 256, 0, stream>>>(Qp, inQ, gma, bta, d_out, flag);
}

// Round 6
// 338.104 us; speedup vs baseline: 1.6175x; 1.0088x over previous
//
#include <hip/hip_runtime.h>
#include <cstdint>
#include <cstddef>

#define DM 1024
#define HEADS 16
#define DHEAD 64
#define SEQ 2048
#define BATCH 2

typedef __bf16 bf16x8 __attribute__((ext_vector_type(8)));
typedef float  f32x4  __attribute__((ext_vector_type(4)));
typedef unsigned short u16;
typedef unsigned int u32;
typedef u16 u16x8 __attribute__((ext_vector_type(8)));
typedef u16 u16x4 __attribute__((ext_vector_type(4)));

__device__ __forceinline__ float bf2f(u16 u){
    union { u32 i; float f; } v; v.i = ((u32)u) << 16; return v.f;
}
__device__ __forceinline__ u16 f2bf(float f){
    union { float f; u32 i; } v; v.f = f;
    u32 r = v.i + 0x7FFF + ((v.i >> 16) & 1);   // RNE
    return (u16)(r >> 16);
}
__device__ __forceinline__ u16 f2bf_rhu(float f){  // cheap round-half-up (positive)
    union { float f; u32 i; } v; v.f = f;
    return (u16)((v.i + 0x8000u) >> 16);
}
__device__ __forceinline__ void gload16(const u16* g, u16* l){
    __builtin_amdgcn_global_load_lds(
        (const __attribute__((address_space(1))) u32*)g,
        (__attribute__((address_space(3))) u32*)l, 16, 0, 0);
}

// ---------------------------------------------------------------------------
// Probe: dtype flag (hdr[0]) + zero the 8 XCD work-claim counters (hdr[1..8]).
// ---------------------------------------------------------------------------
__global__ void k_probe(const u16* __restrict__ q, int* __restrict__ hdr){
    if (threadIdx.x == 0 && blockIdx.x == 0){
        int cnt = 0;
        for (int i = 0; i < 256; i += 2){
            int e = (q[i] >> 7) & 0xFF;
            if (e >= 90 && e <= 141) cnt++;
        }
        hdr[0] = (cnt >= 64) ? 1 : 0;
        #pragma unroll
        for (int c = 1; c <= 8; c++) hdr[c] = 0;
    }
}

// ---------------------------------------------------------------------------
// Convert 3 tensors (fp32|bf16) -> bf16, dst contiguous slots. z = tensor.
// ---------------------------------------------------------------------------
__global__ __launch_bounds__(256) void k_cvt3(const void* __restrict__ s0,
                                              const void* __restrict__ s1,
                                              const void* __restrict__ s2,
                                              u16* __restrict__ dstbase,
                                              const int* __restrict__ flag, int n){
    int z = blockIdx.y;
    const void* src = (z == 0) ? s0 : ((z == 1) ? s1 : s2);
    u16* dst = dstbase + (size_t)z * n;
    int i = (blockIdx.x * 256 + threadIdx.x) * 8;
    if (i >= n) return;
    if (*flag){
        *(u16x8*)&dst[i] = *(const u16x8*)((const u16*)src + i);
    } else {
        const float* s = (const float*)src + i;
        u16x8 o;
        #pragma unroll
        for (int j = 0; j < 8; j++) o[j] = f2bf(s[j]);
        *(u16x8*)&dst[i] = o;
    }
}

// ---------------------------------------------------------------------------
// Transpose+convert 4 weight matrices: dst_z[c][r] = cvt(src_z[r][c]).
// ---------------------------------------------------------------------------
__global__ void k_tcvt4(const void* __restrict__ w0, const void* __restrict__ w1,
                        const void* __restrict__ w2, const void* __restrict__ w3,
                        u16* __restrict__ dstbase,
                        const int* __restrict__ flag, int R, int C){
    __shared__ u16 tile[32][33];
    int z = blockIdx.z;
    const void* src = (z == 0) ? w0 : ((z == 1) ? w1 : ((z == 2) ? w2 : w3));
    u16* dst = dstbase + (size_t)z * R * C;
    bool isbf = (*flag != 0);
    int c0 = blockIdx.x * 32, r0 = blockIdx.y * 32;
    int tx = threadIdx.x, ty = threadIdx.y;     // 32 x 8
    #pragma unroll
    for (int i = 0; i < 32; i += 8){
        size_t idx = (size_t)(r0 + ty + i) * C + c0 + tx;
        tile[ty + i][tx] = isbf ? ((const u16*)src)[idx] : f2bf(((const float*)src)[idx]);
    }
    __syncthreads();
    #pragma unroll
    for (int i = 0; i < 32; i += 8)
        dst[(size_t)(c0 + ty + i) * R + r0 + tx] = tile[tx][ty + i];
}

// ---------------------------------------------------------------------------
// Plain bf16 batched transpose: dst[b][c][r] = src[b][r][c].
// ---------------------------------------------------------------------------
__global__ void k_transpose(const u16* __restrict__ src, u16* __restrict__ dst,
                            int R, int C){
    __shared__ u16 tile[32][33];
    size_t boff = (size_t)blockIdx.z * R * C;
    src += boff; dst += boff;
    int c0 = blockIdx.x * 32, r0 = blockIdx.y * 32;
    int tx = threadIdx.x, ty = threadIdx.y;
    #pragma unroll
    for (int i = 0; i < 32; i += 8)
        tile[ty + i][tx] = src[(size_t)(r0 + ty + i) * C + c0 + tx];
    __syncthreads();
    #pragma unroll
    for (int i = 0; i < 32; i += 8)
        dst[(size_t)(c0 + ty + i) * R + r0 + tx] = tile[tx][ty + i];
}

// ---------------------------------------------------------------------------
// C[M,N] = A[M,K]*Bt[N,K]^T, z-batched. m97-style 128x128 tile, BK=32,
// 256 thr = 4 waves, wave = 64x64 quadrant (4x4 MFMA grid),
// global_load_lds(16B) into XOR-swizzled LDS.
// ---------------------------------------------------------------------------
__global__ __launch_bounds__(256, 2) void k_gemm3z(const u16* __restrict__ A0,
                                                   const u16* __restrict__ Bt0,
                                                   u16* __restrict__ C0,
                                                   size_t strA, size_t strB, size_t strC,
                                                   int M, int N, int K){
    __shared__ u16 lsA[128 * 32];   // row r, 16B-chunk c stored at slot c^(r&3)
    __shared__ u16 lsB[128 * 32];
    int z = blockIdx.z;
    const u16* A  = A0  + strA * z;
    const u16* Bt = Bt0 + strB * z;
    u16* C = C0 + strC * z;
    int m0 = blockIdx.y * 128, n0 = blockIdx.x * 128;
    int t = threadIdx.x, lane = t & 63, w = t >> 6;
    int l15 = lane & 15, quad = lane >> 4;
    int wm = (w & 1) * 64, wn = (w >> 1) * 64;
    int r0 = 32 * w + (lane >> 2);
    int r1 = r0 + 16;
    int c0s = (lane & 3) ^ (r0 & 3);
    int c1s = (lane & 3) ^ (r1 & 3);
    u16* dA0 = &lsA[(32 * w) * 32];       // wave-uniform LDS bases
    u16* dA1 = &lsA[(32 * w + 16) * 32];
    u16* dB0 = &lsB[(32 * w) * 32];
    u16* dB1 = &lsB[(32 * w + 16) * 32];
    f32x4 acc[4][4] = {};
    for (int k0 = 0; k0 < K; k0 += 32){
        __syncthreads();
        gload16(&A [(size_t)(m0 + r0) * K + k0 + c0s * 8], dA0);
        gload16(&A [(size_t)(m0 + r1) * K + k0 + c1s * 8], dA1);
        gload16(&Bt[(size_t)(n0 + r0) * K + k0 + c0s * 8], dB0);
        gload16(&Bt[(size_t)(n0 + r1) * K + k0 + c1s * 8], dB1);
        __syncthreads();
        bf16x8 af[4], bfr[4];
        #pragma unroll
        for (int i = 0; i < 4; i++){
            int row = wm + i * 16 + l15;
            af[i] = *(const bf16x8*)&lsA[row * 32 + ((quad ^ (row & 3)) * 8)];
        }
        #pragma unroll
        for (int j = 0; j < 4; j++){
            int row = wn + j * 16 + l15;
            bfr[j] = *(const bf16x8*)&lsB[row * 32 + ((quad ^ (row & 3)) * 8)];
        }
        #pragma unroll
        for (int i = 0; i < 4; i++)
            #pragma unroll
            for (int j = 0; j < 4; j++)
                acc[i][j] = __builtin_amdgcn_mfma_f32_16x16x32_bf16(af[i], bfr[j], acc[i][j], 0, 0, 0);
    }
    #pragma unroll
    for (int i = 0; i < 4; i++)
        #pragma unroll
        for (int j = 0; j < 4; j++)
            #pragma unroll
            for (int r = 0; r < 4; r++){
                int m = m0 + wm + i * 16 + quad * 4 + r;
                int n = n0 + wn + j * 16 + l15;
                C[(size_t)m * N + n] = f2bf(acc[i][j][r]);
            }
}

// ---------------------------------------------------------------------------
// Fused attention v5, softmax over HEADS. qtile=64, ktile=32, nch k-split.
// Work claiming: each block reads its real XCD id (HW_REG_XCC_ID) and claims
// (combo = xcc-bound (b,chunk), slot = qtile) via atomic counters, so all
// blocks on one XCD stream the SAME 2MB K/V chunk -> L2-resident regardless
// of the dispatch->XCD mapping. Pigeonhole: every block claims exactly one
// of ncombo*32 pairs (each block claims at most once; capacity == #blocks).
// ---------------------------------------------------------------------------
__global__ __launch_bounds__(1024, 4) void k_attn5(const u16* __restrict__ Qp,
                                                   const u16* __restrict__ Kp,
                                                   const u16* __restrict__ Vt,
                                                   u16* __restrict__ c0,
                                                   u16* __restrict__ c1,
                                                   u16* __restrict__ c2,
                                                   u16* __restrict__ c3,
                                                   int* __restrict__ cnt,
                                                   int ncomboM1, int iters){
    __shared__ u16 ebuf[2][16][64][36];   // 144 KB
    __shared__ int s_combo, s_slot;
    int t = threadIdx.x;
    if (t == 0){
        int xcc;
        asm volatile("s_getreg_b32 %0, hwreg(HW_REG_XCC_ID)" : "=s"(xcc));
        int start = xcc & ncomboM1;
        int combo = -1, slot = -1;
        for (int a = 0; a <= ncomboM1 && combo < 0; a++){
            int c = (start + a) & ncomboM1;
            int s = atomicAdd(&cnt[c], 1);
            if (s < 32){ combo = c; slot = s; }
        }
        s_combo = combo; s_slot = slot;
    }
    __syncthreads();
    int combo = s_combo;
    if (combo < 0) return;                 // unreachable; safety for replays
    int b = combo & 1, chunk = combo >> 1;
    int q0 = s_slot * 64;
    int h = t >> 6, lane = t & 63, l15 = lane & 15, quad = lane >> 4;
    u16* outp = (chunk == 0) ? c0 : ((chunk == 1) ? c1 : ((chunk == 2) ? c2 : c3));
    const float cexp = 0.125f * 1.44269504f;
    int kbeg = chunk * (iters << 5);

    bf16x8 qf[4][2];
    #pragma unroll
    for (int sub = 0; sub < 4; sub++)
        #pragma unroll
        for (int ch = 0; ch < 2; ch++)
            qf[sub][ch] = *(const bf16x8*)&Qp[((size_t)(b * SEQ + q0 + sub * 16 + l15)) * DM
                                             + h * DHEAD + ch * 32 + quad * 8];

    f32x4 oacc[4][4] = {};
    int sq = t >> 4, sku = (t & 15) * 2;   // softmax owns (q=sq, k=sku..sku+1)

    auto score_phase = [&](int it){
        int k0 = kbeg + (it << 5), bf = it & 1;
        #pragma unroll
        for (int kt = 0; kt < 2; kt++){
            const u16* kb = Kp + ((size_t)(b * SEQ + k0 + kt * 16 + l15)) * DM + h * DHEAD + quad * 8;
            bf16x8 kf0 = *(const bf16x8*)(kb);
            bf16x8 kf1 = *(const bf16x8*)(kb + 32);
            #pragma unroll
            for (int sub = 0; sub < 4; sub++){
                f32x4 sc = {};
                sc = __builtin_amdgcn_mfma_f32_16x16x32_bf16(qf[sub][0], kf0, sc, 0, 0, 0);
                sc = __builtin_amdgcn_mfma_f32_16x16x32_bf16(qf[sub][1], kf1, sc, 0, 0, 0);
                #pragma unroll
                for (int r = 0; r < 4; r++)
                    ebuf[bf][h][sub * 16 + quad * 4 + r][kt * 16 + l15] =
                        f2bf_rhu(exp2f(sc[r] * cexp));
            }
        }
    };

    score_phase(0);
    for (int it = 0; it < iters; it++){
        int bf = it & 1;
        __syncthreads();                       // B1: e(it) complete
        {   // softmax across 16 heads, in place (u32 = 2 packed bf16)
            u32 ev[16];
            float s0 = 0.f, s1 = 0.f;
            #pragma unroll
            for (int hh = 0; hh < 16; hh++){
                u32 u = *(const u32*)&ebuf[bf][hh][sq][sku];
                ev[hh] = u;
                union { u32 i; float f; } lo, hi;
                lo.i = u << 16; hi.i = u & 0xFFFF0000u;
                s0 += lo.f; s1 += hi.f;
            }
            float r0 = __builtin_amdgcn_rcpf(s0);
            float r1 = __builtin_amdgcn_rcpf(s1);
            #pragma unroll
            for (int hh = 0; hh < 16; hh++){
                union { u32 i; float f; } lo, hi, p0, p1;
                lo.i = ev[hh] << 16; hi.i = ev[hh] & 0xFFFF0000u;
                p0.f = lo.f * r0; p1.f = hi.f * r1;
                *(u32*)&ebuf[bf][hh][sq][sku] =
                    ((p0.i + 0x8000u) >> 16) | ((p1.i + 0x8000u) & 0xFFFF0000u);
            }
        }
        __syncthreads();                       // B2: P(it) ready
        int k0 = kbeg + (it << 5);
        bf16x8 pa[4];
        #pragma unroll
        for (int sub = 0; sub < 4; sub++){
            const u16* pp = &ebuf[bf][h][sub * 16 + l15][quad * 8];
            union { bf16x8 v; u16x4 q[2]; } pu;
            pu.q[0] = *(const u16x4*)pp;
            pu.q[1] = *(const u16x4*)(pp + 4);
            pa[sub] = pu.v;
        }
        #pragma unroll
        for (int vt = 0; vt < 4; vt++){
            bf16x8 vf = *(const bf16x8*)&Vt[((size_t)b * DM + h * DHEAD + vt * 16 + l15) * SEQ
                                            + k0 + quad * 8];
            #pragma unroll
            for (int sub = 0; sub < 4; sub++)
                oacc[sub][vt] = __builtin_amdgcn_mfma_f32_16x16x32_bf16(pa[sub], vf, oacc[sub][vt], 0, 0, 0);
        }
        if (it + 1 < iters) score_phase(it + 1);
    }
    #pragma unroll
    for (int sub = 0; sub < 4; sub++)
        #pragma unroll
        for (int vt = 0; vt < 4; vt++)
            #pragma unroll
            for (int r = 0; r < 4; r++){
                int q = q0 + sub * 16 + quad * 4 + r;
                int n = h * DHEAD + vt * 16 + l15;
                outp[((size_t)b * SEQ + q) * DM + n] = f2bf(oacc[sub][vt][r]);
            }
}

// ---------------------------------------------------------------------------
// dst = c0+c1(+c2+c3) (bf16). dst may alias c0 (same-index load-then-store).
// ---------------------------------------------------------------------------
__global__ __launch_bounds__(256) void k_reduce(const u16* __restrict__ a,
                                                const u16* __restrict__ b,
                                                const u16* __restrict__ c,
                                                const u16* __restrict__ d,
                                                u16* __restrict__ dst, int n, int nch){
    int i = (blockIdx.x * 256 + threadIdx.x) * 8;
    if (i >= n) return;
    u16x8 x = *(const u16x8*)&a[i];
    u16x8 y = *(const u16x8*)&b[i];
    u16x8 o;
    if (nch == 4){
        u16x8 zc = *(const u16x8*)&c[i];
        u16x8 zd = *(const u16x8*)&d[i];
        #pragma unroll
        for (int j = 0; j < 8; j++)
            o[j] = f2bf((bf2f(x[j]) + bf2f(y[j])) + (bf2f(zc[j]) + bf2f(zd[j])));
    } else {
        #pragma unroll
        for (int j = 0; j < 8; j++) o[j] = f2bf(bf2f(x[j]) + bf2f(y[j]));
    }
    *(u16x8*)&dst[i] = o;
}

// ---------------------------------------------------------------------------
// Residual + LayerNorm over last dim (1024). One block per row.
// ---------------------------------------------------------------------------
__global__ __launch_bounds__(256) void k_ln(const u16* __restrict__ O,
                                            const void* __restrict__ Qin,
                                            const void* __restrict__ gamma,
                                            const void* __restrict__ beta,
                                            void* __restrict__ out,
                                            const int* __restrict__ flag){
    __shared__ float red[4][2];
    bool isbf = (*flag != 0);
    int row = blockIdx.x;
    int t = threadIdx.x;
    const u16* op = O + (size_t)row * DM;
    float xv[4];
    float s1 = 0.f, s2 = 0.f;
    #pragma unroll
    for (int i = 0; i < 4; i++){
        int idx = i * 256 + t;
        float q = isbf ? bf2f(((const u16*)Qin)[(size_t)row * DM + idx])
                       : ((const float*)Qin)[(size_t)row * DM + idx];
        float x = bf2f(op[idx]) + q;
        xv[i] = x; s1 += x; s2 += x * x;
    }
    #pragma unroll
    for (int off = 32; off; off >>= 1){
        s1 += __shfl_down(s1, off);
        s2 += __shfl_down(s2, off);
    }
    int w = t >> 6, lane = t & 63;
    if (lane == 0){ red[w][0] = s1; red[w][1] = s2; }
    __syncthreads();
    float S1 = red[0][0] + red[1][0] + red[2][0] + red[3][0];
    float S2 = red[0][1] + red[1][1] + red[2][1] + red[3][1];
    float mu  = S1 * (1.0f / DM);
    float var = S2 * (1.0f / DM) - mu * mu;
    float rstd = rsqrtf(var + 1e-5f);
    #pragma unroll
    for (int i = 0; i < 4; i++){
        int idx = i * 256 + t;
        float g = isbf ? bf2f(((const u16*)gamma)[idx]) : ((const float*)gamma)[idx];
        float bb= isbf ? bf2f(((const u16*)beta )[idx]) : ((const float*)beta )[idx];
        float y = (xv[i] - mu) * rstd * g + bb;
        if (isbf) ((u16*)out)[(size_t)row * DM + idx] = f2bf(y);
        else      ((float*)out)[(size_t)row * DM + idx] = y;
    }
}

// ---------------------------------------------------------------------------
extern "C" void kernel_launch(void* const* d_in, const int* in_sizes, int n_in,
                              void* d_out, int out_size, void* d_ws, size_t ws_size,
                              hipStream_t stream){
    (void)in_sizes; (void)n_in; (void)out_size;
    const void* inQ = d_in[0];
    const void* inK = d_in[1];
    const void* inV = d_in[2];
    const void* wQ  = d_in[3];
    const void* wK  = d_in[4];
    const void* wV  = d_in[5];
    const void* wO  = d_in[6];
    const void* gma = d_in[7];
    const void* bta = d_in[8];

    int* hdr  = (int*)d_ws;                    // [0]=flag, [1..8]=claim counters
    int* flag = hdr;
    int* cnt  = hdr + 1;
    u16* base = (u16*)d_ws + 64;               // 128 B header

    const size_t MB1 = 1024u * 1024u;          // elements
    const size_t M4  = 4u * MB1;
    u16* Qi  = base + 0;                       // slot0: bf16 Q input -> ctxp0/cx
    u16* Ki  = base + 1 * M4;                  // slot1: bf16 K input -> Vt
    u16* Vi  = base + 2 * M4;                  // slot2: bf16 V input -> ctxp2
    u16* WtQ = base + 3 * M4;                  // slot3: 4 x W^T [1024,1024]
    u16* WtO = WtQ + 3 * MB1;
    u16* Qp  = base + 4 * M4;                  // slot4: Q proj -> Ob
    u16* Kp  = base + 5 * M4;                  // slot5: K proj
    u16* Vp  = base + 6 * M4;                  // slot6: V proj -> ctxp1
    u16* ext = base + 7 * M4;                  // slot7: ctxp3 (if ws allows)
    u16* Vt    = Ki;
    u16* ctxp0 = Qi;
    u16* ctxp1 = Vp;
    u16* ctxp2 = Vi;

    size_t need4 = 128 + 8 * M4 * sizeof(u16);
    int nch = (ws_size >= need4) ? 4 : 2;
    u16* ctxp3 = (nch == 4) ? ext : ctxp2;     // dummy when nch==2 (never selected)
    int ncomboM1 = 2 * nch - 1;
    int iters   = (nch == 4) ? 16 : 32;        // keys per chunk / 32
    int ablocks = 32 * 2 * nch;

    k_probe<<<1, 64, 0, stream>>>((const u16*)inQ, hdr);

    const int nIn = BATCH * SEQ * DM;          // 4M
    k_cvt3<<<dim3(nIn / 2048, 3), 256, 0, stream>>>(inQ, inK, inV, base, flag, nIn);

    k_tcvt4<<<dim3(32, 32, 4), dim3(32, 8), 0, stream>>>(wQ, wK, wV, wO, WtQ, flag, 1024, 1024);

    // Q/K/V projections in one dispatch (z selects A/Bt/C triple)
    k_gemm3z<<<dim3(8, 32, 3), 256, 0, stream>>>(Qi, WtQ, Qp, M4, MB1, M4, 4096, 1024, 1024);

    k_transpose<<<dim3(32, 64, 2), dim3(32, 8), 0, stream>>>(Vp, Vt, 2048, 1024);

    k_attn5<<<ablocks, 1024, 0, stream>>>(Qp, Kp, Vt, ctxp0, ctxp1, ctxp2, ctxp3,
                                          cnt, ncomboM1, iters);

    k_reduce<<<nIn / 2048, 256, 0, stream>>>(ctxp0, ctxp1, ctxp2, ctxp3, ctxp0, nIn, nch);

    k_gemm3z<<<dim3(8, 32, 1), 256, 0, stream>>>(ctxp0, WtO, Qp, 0, 0, 0, 4096, 1024, 1024);

    k_ln<<<4096, 256, 0, stream>>>(Qp, inQ, gma, bta, d_out, flag);
}